// Round 18
// baseline (281.725 us; speedup 1.0000x reference)
//
#include <hip/hip_runtime.h>
#include <hip/hip_bf16.h>
#include <cmath>

#define N_NODESC 20000
#define E_RAW    320000
#define E_TOTC   340000   // + self loops
#define HEADSC   4
#define FC       256      // HEADS*HID
#define NEG_SLOPE 0.2f

typedef __attribute__((ext_vector_type(8))) short short8v;   // 8 bf16 = 4 VGPR
typedef __attribute__((ext_vector_type(4))) float f32x4;

__device__ __forceinline__ int dstOf(const int* ei, int e) {
  return (e < E_RAW) ? ei[E_RAW + e] : (e - E_RAW);
}
__device__ __forceinline__ int srcOf(const int* ei, int e) {
  return (e < E_RAW) ? ei[e] : (e - E_RAW);
}
__device__ __forceinline__ float lrelu(float v) { return v > 0.f ? v : NEG_SLOPE * v; }

__device__ __forceinline__ unsigned short f2bf(float f) {
  __hip_bfloat16 h = __float2bfloat16(f);           // RN
  return reinterpret_cast<unsigned short&>(h);
}
__device__ __forceinline__ float bf2f(unsigned short u) {
  return __uint_as_float(((unsigned int)u) << 16);
}

// Order-invariant float atomic max via int/uint monotone encoding.
__device__ __forceinline__ void atomicMaxF(float* addr, float val) {
  if (val >= 0.f) atomicMax((int*)addr, __float_as_int(val));
  else            atomicMin((unsigned int*)addr, (unsigned int)__float_as_int(val));
}

// ---- mega prep: x split + W1/W2 transpose-split + deg zero + amax init ----
__global__ void mega_prep(const float* __restrict__ x,
                          unsigned short* __restrict__ xhi, unsigned short* __restrict__ xlo,
                          const float* __restrict__ W1,
                          unsigned short* __restrict__ w1hi, unsigned short* __restrict__ w1lo,
                          const float* __restrict__ W2,
                          unsigned short* __restrict__ w2hi, unsigned short* __restrict__ w2lo,
                          int* __restrict__ deg, float* __restrict__ amax) {
  const int bid = blockIdx.x, t = threadIdx.x;
  if (bid < 10000) {                                 // x: 20000*128 = 10000 blocks exact
    int i = bid * 256 + t;
    float v = x[i];
    unsigned short hh = f2bf(v);
    xhi[i] = hh; xlo[i] = f2bf(v - bf2f(hh));
  } else if (bid < 10128) {                          // W1: 256*128 = 128 blocks
    int idx = (bid - 10000) * 256 + t;
    int c = idx >> 7, k = idx & 127;
    float v = W1[k * FC + c];
    unsigned short hh = f2bf(v);
    w1hi[c * 128 + k] = hh; w1lo[c * 128 + k] = f2bf(v - bf2f(hh));
  } else if (bid < 10384) {                          // W2: 256*256 = 256 blocks
    int idx = (bid - 10128) * 256 + t;
    int c = idx >> 8, k = idx & 255;
    float v = W2[k * FC + c];
    unsigned short hh = f2bf(v);
    w2hi[c * 256 + k] = hh; w2lo[c * 256 + k] = f2bf(v - bf2f(hh));
  } else {                                           // deg zero + amax init: 79 blocks
    int i = (bid - 10384) * 256 + t;
    if (i < N_NODESC) deg[i] = 0;
    else if (i < N_NODESC + 8) amax[i - N_NODESC] = -INFINITY;
  }
}

// ---------- MFMA GEMM + fused alpha + global-as-max ------------------------
// 32 rows/block (625 blocks exact), 256 threads = 4 waves (wave w = head w's
// 64 cols). A (hi+lo) staged in LDS, XOR-16B swizzled. W streams from L2.
// hb written HEAD-MAJOR: hb[h][n][64] (per-head table = 2.56MB, L2-resident).
template<int K>
__global__ void __launch_bounds__(256) mfma_gemm(
    const unsigned short* __restrict__ Ahi, const unsigned short* __restrict__ Alo,
    const unsigned short* __restrict__ WhiT, const unsigned short* __restrict__ WloT,
    const float* __restrict__ a_src, const float* __restrict__ a_dst,
    unsigned short* __restrict__ hb, float* __restrict__ as, float* __restrict__ ad,
    float* __restrict__ asmax) {
  __shared__ unsigned short xsh[32 * K];
  __shared__ unsigned short xsl[32 * K];
  __shared__ float asred[32][4];
  __shared__ float adred[32][4];
  __shared__ float wmax[2][4];
  const int t = threadIdx.x;
  const int w = t >> 6, l = t & 63;
  const int n0 = blockIdx.x * 32;                   // 20000/32 = 625 exact
  const int r16 = l & 15;
  const int kq = l >> 4;
  const int col0 = w * 64;

  // ---- stage A tile (hi+lo) into LDS, swizzled ----
  const int KC = K / 8;                             // 16B chunks per row
  for (int c = t; c < 32 * KC; c += 256) {
    int row = c / KC, k16 = c - row * KC;
    int bo = (row * K + k16 * 8) * 2;
    int swz = bo ^ ((row & 7) << 4);
    *(short8v*)((char*)xsh + swz) = *(const short8v*)(Ahi + (long)(n0 + row) * K + k16 * 8);
    *(short8v*)((char*)xsl + swz) = *(const short8v*)(Alo + (long)(n0 + row) * K + k16 * 8);
  }
  __syncthreads();

  f32x4 acc[2][4];
#pragma unroll
  for (int rt = 0; rt < 2; ++rt)
#pragma unroll
    for (int ct = 0; ct < 4; ++ct) acc[rt][ct] = f32x4{0.f, 0.f, 0.f, 0.f};

  for (int ks = 0; ks < K; ks += 32) {
    const int kb = ks + kq * 8;
    short8v aHi[2], aLo[2];
#pragma unroll
    for (int rt = 0; rt < 2; ++rt) {
      int bo = ((rt * 16 + r16) * K + kb) * 2;
      int swz = bo ^ ((r16 & 7) << 4);
      aHi[rt] = *(const short8v*)((const char*)xsh + swz);
      aLo[rt] = *(const short8v*)((const char*)xsl + swz);
    }
#pragma unroll
    for (int ct = 0; ct < 4; ++ct) {
      const long wrow = (long)(col0 + ct * 16 + r16) * K + kb;
      short8v wHi = *(const short8v*)(WhiT + wrow);
      short8v wLo = *(const short8v*)(WloT + wrow);
#pragma unroll
      for (int rt = 0; rt < 2; ++rt) {
        acc[rt][ct] = __builtin_amdgcn_mfma_f32_16x16x32_bf16(aHi[rt], wHi, acc[rt][ct], 0, 0, 0);
        acc[rt][ct] = __builtin_amdgcn_mfma_f32_16x16x32_bf16(aHi[rt], wLo, acc[rt][ct], 0, 0, 0);
        acc[rt][ct] = __builtin_amdgcn_mfma_f32_16x16x32_bf16(aLo[rt], wHi, acc[rt][ct], 0, 0, 0);
      }
    }
  }

  float asv[4], adv[4];
#pragma unroll
  for (int ct = 0; ct < 4; ++ct) {
    int c = col0 + ct * 16 + r16;
    asv[ct] = a_src[c];
    adv[ct] = a_dst[c];
  }
#pragma unroll
  for (int rt = 0; rt < 2; ++rt) {
#pragma unroll
    for (int j = 0; j < 4; ++j) {
      const int r = rt * 16 + kq * 4 + j;           // row within block (0..31)
      const int g = n0 + r;                         // always < 20000
      // head-major hb: wave w == head w
#pragma unroll
      for (int ct = 0; ct < 4; ++ct)
        hb[((long)w * N_NODESC + g) * 64 + ct * 16 + r16] = f2bf(acc[rt][ct][j]);
      float ps = acc[rt][0][j] * asv[0] + acc[rt][1][j] * asv[1]
               + acc[rt][2][j] * asv[2] + acc[rt][3][j] * asv[3];
      float pd = acc[rt][0][j] * adv[0] + acc[rt][1][j] * adv[1]
               + acc[rt][2][j] * adv[2] + acc[rt][3][j] * adv[3];
      for (int off = 8; off; off >>= 1) {
        ps += __shfl_down(ps, off, 16);
        pd += __shfl_down(pd, off, 16);
      }
      if (r16 == 0) {
        asred[r][w] = ps;
        adred[r][w] = pd;
      }
    }
  }
  __syncthreads();
  if (t < 128) {                                    // 2 waves cover 32 rows
    const int rr = t >> 2, hh = t & 3;
    const int g = n0 + rr;
    float va = asred[rr][hh];
    as[(long)g * HEADSC + hh] = va;
    ad[(long)g * HEADSC + hh] = adred[rr][hh];
    float mv = va;
    for (int off = 32; off >= 4; off >>= 1) mv = fmaxf(mv, __shfl_down(mv, off, 64));
    if (l < 4) wmax[t >> 6][l] = mv;
  }
  __syncthreads();
  if (t < 4) atomicMaxF(&asmax[t], fmaxf(wmax[0][t], wmax[1][t]));
}

// ----------------------------- CSR build -----------------------------------
__global__ void deg_count(const int* __restrict__ ei, int* __restrict__ deg) {
  int e = blockIdx.x * 256 + threadIdx.x;
  if (e >= E_TOTC) return;
  atomicAdd(&deg[dstOf(ei, e)], 1);
}

// 1024-thread single-block scan, 2 barriers
__global__ void scan_kernel(const int* __restrict__ deg, int* __restrict__ row_ptr,
                            int* __restrict__ cursor) {
  const int t = threadIdx.x;
  const int lane = t & 63, wid = t >> 6;           // 16 waves
  const int PER = (N_NODESC + 1023) / 1024;        // 20
  const int base = t * PER;
  int own = 0;
  for (int i = 0; i < PER; ++i) {
    int idx = base + i;
    if (idx < N_NODESC) own += deg[idx];
  }
  int inc = own;
  for (int off = 1; off < 64; off <<= 1) {
    int v = __shfl_up(inc, off, 64);
    if (lane >= off) inc += v;
  }
  __shared__ int wtot[16], woff[16];
  if (lane == 63) wtot[wid] = inc;
  __syncthreads();
  if (t == 0) {
    int r = 0;
    for (int i = 0; i < 16; ++i) { woff[i] = r; r += wtot[i]; }
  }
  __syncthreads();
  int run = woff[wid] + inc - own;
  for (int i = 0; i < PER; ++i) {
    int idx = base + i;
    if (idx < N_NODESC) {
      row_ptr[idx] = run;
      cursor[idx]  = run;
      run += deg[idx];
    }
  }
  if (t == 1023) row_ptr[N_NODESC] = run;          // = E_TOTC
}

__global__ void fill_kernel(const int* __restrict__ ei, int* __restrict__ cursor,
                            int* __restrict__ col_src) {
  int e = blockIdx.x * 256 + threadIdx.x;
  if (e >= E_TOTC) return;
  int d = dstOf(ei, e);
  int pos = atomicAdd(&cursor[d], 1);
  col_src[pos] = srcOf(ei, e);
}

// --- FUSED softmax+agg, WAVE PER (NODE, HEAD) — per-head L2-resident gather.
// head = blockIdx.x & 3 -> XCD round-robin pins head h to XCDs {h, h+4}.
// Block = 4 waves = 4 nodes of the SAME head; lane = 1 channel (2B gather).
// MODE 0: write ELU'd act (row-major, hi/lo). MODE 1: per-head W3 partials.
template<int MODE>
__global__ void __launch_bounds__(256) fused_sa(
    const int* __restrict__ row_ptr, const int* __restrict__ col_src,
    const float* __restrict__ asf, const float* __restrict__ adf,
    const float* __restrict__ asmax,
    const unsigned short* __restrict__ hb, const float* __restrict__ b,
    unsigned short* __restrict__ out_hi, unsigned short* __restrict__ out_lo,
    const float* __restrict__ W3, float* __restrict__ h3p) {
  const int l = threadIdx.x & 63, wv = threadIdx.x >> 6;
  const int h = blockIdx.x & 3;
  const int d = (blockIdx.x >> 2) * 4 + wv;         // 5000 groups * 4 = 20000
  const int j0 = row_ptr[d], j1 = row_ptr[d + 1];
  const float advh = adf[d * 4 + h];
  const float mh = lrelu(asmax[h] + advh);

  const unsigned short* hbh = hb + (long)h * N_NODESC * 64;
  float acc = 0.f, sm = 0.f;
  int j = j0;
  for (; j + 8 <= j1; j += 8) {
    int            s[8];
    float          av[8];
    unsigned short v[8];
#pragma unroll
    for (int u = 0; u < 8; ++u) s[u] = col_src[j + u];
#pragma unroll
    for (int u = 0; u < 8; ++u) av[u] = asf[s[u] * 4 + h];
#pragma unroll
    for (int u = 0; u < 8; ++u) v[u] = hbh[(long)s[u] * 64 + l];
#pragma unroll
    for (int u = 0; u < 8; ++u) {
      float e = expf(lrelu(av[u] + advh) - mh);
      sm += e;
      acc = fmaf(e, bf2f(v[u]), acc);
    }
  }
  for (; j < j1; ++j) {
    int s = col_src[j];
    float e = expf(lrelu(asf[s * 4 + h] + advh) - mh);
    unsigned short v = hbh[(long)s * 64 + l];
    sm += e;
    acc = fmaf(e, bf2f(v), acc);
  }
  float o = acc / sm + b[h * 64 + l];
  o = o > 0.f ? o : expm1f(o);                      // ELU

  if (MODE == 0) {
    unsigned short hi = f2bf(o);
    unsigned short lo = f2bf(o - bf2f(hi));
    out_hi[(long)d * FC + h * 64 + l] = hi;
    out_lo[(long)d * FC + h * 64 + l] = lo;
  } else {
    // per-head W3 partial: p = sum_c o_c * W3[h*64+c]
    float p = o * W3[h * 64 + l];
    for (int off = 32; off; off >>= 1) p += __shfl_down(p, off, 64);
    if (l == 0) h3p[(long)h * N_NODESC + d] = p;
  }
}

// --- combine per-head W3 partials -> h3, layer-3 alphas --------------------
__global__ void h3_combine(const float* __restrict__ h3p, const float* __restrict__ asc3,
                           const float* __restrict__ adc3, float* __restrict__ h3,
                           float* __restrict__ a3s, float* __restrict__ a3d) {
  int i = blockIdx.x * 256 + threadIdx.x;
  if (i >= N_NODESC) return;
  float s = h3p[i] + h3p[N_NODESC + i] + h3p[2 * N_NODESC + i] + h3p[3 * N_NODESC + i];
  h3[i]  = s;
  a3s[i] = s * asc3[0];
  a3d[i] = s * adc3[0];
}

// --- FUSED layer3 softmax+agg: out = sum(e*h3)/sum(e), wave per node -------
__global__ void __launch_bounds__(256) fused_sa3(
    const int* __restrict__ row_ptr, const int* __restrict__ col_src,
    const float* __restrict__ as, const float* __restrict__ ad,
    const float* __restrict__ h3, const float* __restrict__ b3,
    float* __restrict__ out) {
  const int wv = threadIdx.x >> 6, l = threadIdx.x & 63;
  const int d = blockIdx.x * 4 + wv;
  if (d >= N_NODESC) return;
  const int j0 = row_ptr[d], j1 = row_ptr[d + 1];
  const float adv = ad[d];
  float mx = -INFINITY;
  for (int j = j0 + l; j < j1; j += 64)
    mx = fmaxf(mx, lrelu(as[col_src[j]] + adv));
  for (int off = 32; off; off >>= 1) mx = fmaxf(mx, __shfl_xor(mx, off, 64));
  float sm = 0.f, acc = 0.f;
  for (int j = j0 + l; j < j1; j += 64) {
    int s = col_src[j];
    float e = expf(lrelu(as[s] + adv) - mx);
    sm += e;
    acc = fmaf(e, h3[s], acc);
  }
  for (int off = 32; off; off >>= 1) {
    sm  += __shfl_xor(sm, off, 64);
    acc += __shfl_xor(acc, off, 64);
  }
  if (l == 0) out[d] = acc / sm + b3[0];
}

extern "C" void kernel_launch(void* const* d_in, const int* in_sizes, int n_in,
                              void* d_out, int out_size, void* d_ws, size_t ws_size,
                              hipStream_t stream) {
  const float* x    = (const float*)d_in[0];
  const int*   ei   = (const int*)d_in[1];
  const float* W1   = (const float*)d_in[2];
  const float* as1  = (const float*)d_in[3];
  const float* ad1  = (const float*)d_in[4];
  const float* b1   = (const float*)d_in[5];
  const float* W2   = (const float*)d_in[6];
  const float* as2  = (const float*)d_in[7];
  const float* ad2  = (const float*)d_in[8];
  const float* b2   = (const float*)d_in[9];
  const float* W3   = (const float*)d_in[10];
  const float* as3  = (const float*)d_in[11];
  const float* ad3  = (const float*)d_in[12];
  const float* b3   = (const float*)d_in[13];
  float* out = (float*)d_out;

  float* ws = (float*)d_ws;
  size_t off = 0;
  float* wAs   = ws + off; off += (size_t)N_NODESC * HEADSC;
  float* wAd   = ws + off; off += (size_t)N_NODESC * HEADSC;
  float* h3    = ws + off; off += N_NODESC;
  float* a3s   = ws + off; off += N_NODESC;
  float* a3d   = ws + off; off += N_NODESC;
  float* h3p   = ws + off; off += (size_t)N_NODESC * HEADSC;
  float* amax  = ws + off; off += 8;                // [0..3]=layer1, [4..7]=layer2
  int* deg     = (int*)(ws + off); off += N_NODESC;
  int* row_ptr = (int*)(ws + off); off += N_NODESC + 1;
  int* cursor  = (int*)(ws + off); off += N_NODESC;
  int* col_src = (int*)(ws + off); off += E_TOTC;
  off = (off + 3) & ~(size_t)3;                     // 16B align for bf16 vectors
  unsigned short* hb     = (unsigned short*)(ws + off); off += (size_t)N_NODESC * 128;
  unsigned short* act_hi = (unsigned short*)(ws + off); off += (size_t)N_NODESC * 128;
  unsigned short* act_lo = (unsigned short*)(ws + off); off += (size_t)N_NODESC * 128;
  unsigned short* xhi    = (unsigned short*)(ws + off); off += (size_t)N_NODESC * 64;
  unsigned short* xlo    = (unsigned short*)(ws + off); off += (size_t)N_NODESC * 64;
  unsigned short* W1hiT  = (unsigned short*)(ws + off); off += 16384;   // 32768 ush
  unsigned short* W1loT  = (unsigned short*)(ws + off); off += 16384;
  unsigned short* W2hiT  = (unsigned short*)(ws + off); off += 32768;   // 65536 ush
  unsigned short* W2loT  = (unsigned short*)(ws + off); off += 32768;

  const int gridE  = (E_TOTC + 255) / 256;
  const int gridN  = (N_NODESC + 255) / 256;
  const int gridN4 = (N_NODESC + 3) / 4;
  const int gemmG  = N_NODESC / 32;                 // 625, exact

  // ---------------- prep (1 dispatch) + CSR build --------------------------
  mega_prep<<<10463, 256, 0, stream>>>(x, xhi, xlo, W1, W1hiT, W1loT,
                                       W2, W2hiT, W2loT, deg, amax);
  deg_count<<<gridE, 256, 0, stream>>>(ei, deg);
  scan_kernel<<<1, 1024, 0, stream>>>(deg, row_ptr, cursor);
  fill_kernel<<<gridE, 256, 0, stream>>>(ei, cursor, col_src);

  // ---------------- layer 1 (K=128) ----------------
  mfma_gemm<128><<<gemmG, 256, 0, stream>>>(xhi, xlo, W1hiT, W1loT, as1, ad1,
                                            hb, wAs, wAd, amax);
  fused_sa<0><<<N_NODESC, 256, 0, stream>>>(row_ptr, col_src, wAs, wAd, amax,
                                            hb, b1, act_hi, act_lo, nullptr, nullptr);

  // ---------------- layer 2 (K=256), per-head gemm3 partials ---------------
  mfma_gemm<256><<<gemmG, 256, 0, stream>>>(act_hi, act_lo, W2hiT, W2loT, as2, ad2,
                                            hb, wAs, wAd, amax + 4);
  fused_sa<1><<<N_NODESC, 256, 0, stream>>>(row_ptr, col_src, wAs, wAd, amax + 4,
                                            hb, b2, nullptr, nullptr, W3, h3p);
  h3_combine<<<gridN, 256, 0, stream>>>(h3p, as3, ad3, h3, a3s, a3d);

  // ---------------- layer 3 (heads=1, out=1) ----------------
  fused_sa3<<<gridN4, 256, 0, stream>>>(row_ptr, col_src, a3s, a3d, h3, b3, out);
}

// Round 19
// 218.708 us; speedup vs baseline: 1.2881x; 1.2881x over previous
//
#include <hip/hip_runtime.h>
#include <hip/hip_bf16.h>
#include <cmath>

#define N_NODESC 20000
#define E_RAW    320000
#define E_TOTC   340000   // + self loops
#define HEADSC   4
#define FC       256      // HEADS*HID
#define NEG_SLOPE 0.2f

typedef __attribute__((ext_vector_type(8))) short short8v;   // 8 bf16 = 4 VGPR
typedef __attribute__((ext_vector_type(4))) float f32x4;

__device__ __forceinline__ int dstOf(const int* ei, int e) {
  return (e < E_RAW) ? ei[E_RAW + e] : (e - E_RAW);
}
__device__ __forceinline__ int srcOf(const int* ei, int e) {
  return (e < E_RAW) ? ei[e] : (e - E_RAW);
}
__device__ __forceinline__ float lrelu(float v) { return v > 0.f ? v : NEG_SLOPE * v; }

__device__ __forceinline__ unsigned short f2bf(float f) {
  __hip_bfloat16 h = __float2bfloat16(f);           // RN
  return reinterpret_cast<unsigned short&>(h);
}
__device__ __forceinline__ float bf2f(unsigned short u) {
  return __uint_as_float(((unsigned int)u) << 16);
}

// Order-invariant float atomic max via int/uint monotone encoding.
__device__ __forceinline__ void atomicMaxF(float* addr, float val) {
  if (val >= 0.f) atomicMax((int*)addr, __float_as_int(val));
  else            atomicMin((unsigned int*)addr, (unsigned int)__float_as_int(val));
}

// ---- mega prep: x split + W1/W2 transpose-split + deg zero + amax init ----
__global__ void mega_prep(const float* __restrict__ x,
                          unsigned short* __restrict__ xhi, unsigned short* __restrict__ xlo,
                          const float* __restrict__ W1,
                          unsigned short* __restrict__ w1hi, unsigned short* __restrict__ w1lo,
                          const float* __restrict__ W2,
                          unsigned short* __restrict__ w2hi, unsigned short* __restrict__ w2lo,
                          int* __restrict__ deg, float* __restrict__ amax) {
  const int bid = blockIdx.x, t = threadIdx.x;
  if (bid < 10000) {                                 // x: 20000*128 = 10000 blocks exact
    int i = bid * 256 + t;
    float v = x[i];
    unsigned short hh = f2bf(v);
    xhi[i] = hh; xlo[i] = f2bf(v - bf2f(hh));
  } else if (bid < 10128) {                          // W1: 256*128 = 128 blocks
    int idx = (bid - 10000) * 256 + t;
    int c = idx >> 7, k = idx & 127;
    float v = W1[k * FC + c];
    unsigned short hh = f2bf(v);
    w1hi[c * 128 + k] = hh; w1lo[c * 128 + k] = f2bf(v - bf2f(hh));
  } else if (bid < 10384) {                          // W2: 256*256 = 256 blocks
    int idx = (bid - 10128) * 256 + t;
    int c = idx >> 8, k = idx & 255;
    float v = W2[k * FC + c];
    unsigned short hh = f2bf(v);
    w2hi[c * 256 + k] = hh; w2lo[c * 256 + k] = f2bf(v - bf2f(hh));
  } else {                                           // deg zero + amax init: 79 blocks
    int i = (bid - 10384) * 256 + t;
    if (i < N_NODESC) deg[i] = 0;
    else if (i < N_NODESC + 8) amax[i - N_NODESC] = -INFINITY;
  }
}

// ---------- MFMA GEMM + fused alpha + global-as-max ------------------------
// 32 rows/block (625 blocks exact), 256 threads = 4 waves (wave w = head w's
// 64 cols). A (hi+lo) staged in LDS, XOR-16B swizzled. W streams from L2.
// hb row-major [n][256] (R17 layout — one edge walk serves all 4 heads).
template<int K>
__global__ void __launch_bounds__(256) mfma_gemm(
    const unsigned short* __restrict__ Ahi, const unsigned short* __restrict__ Alo,
    const unsigned short* __restrict__ WhiT, const unsigned short* __restrict__ WloT,
    const float* __restrict__ a_src, const float* __restrict__ a_dst,
    unsigned short* __restrict__ hb, float* __restrict__ as, float* __restrict__ ad,
    float* __restrict__ asmax) {
  __shared__ unsigned short xsh[32 * K];
  __shared__ unsigned short xsl[32 * K];
  __shared__ float asred[32][4];
  __shared__ float adred[32][4];
  __shared__ float wmax[2][4];
  const int t = threadIdx.x;
  const int w = t >> 6, l = t & 63;
  const int n0 = blockIdx.x * 32;                   // 20000/32 = 625 exact
  const int r16 = l & 15;
  const int kq = l >> 4;
  const int col0 = w * 64;

  // ---- stage A tile (hi+lo) into LDS, swizzled ----
  const int KC = K / 8;                             // 16B chunks per row
  for (int c = t; c < 32 * KC; c += 256) {
    int row = c / KC, k16 = c - row * KC;
    int bo = (row * K + k16 * 8) * 2;
    int swz = bo ^ ((row & 7) << 4);
    *(short8v*)((char*)xsh + swz) = *(const short8v*)(Ahi + (long)(n0 + row) * K + k16 * 8);
    *(short8v*)((char*)xsl + swz) = *(const short8v*)(Alo + (long)(n0 + row) * K + k16 * 8);
  }
  __syncthreads();

  f32x4 acc[2][4];
#pragma unroll
  for (int rt = 0; rt < 2; ++rt)
#pragma unroll
    for (int ct = 0; ct < 4; ++ct) acc[rt][ct] = f32x4{0.f, 0.f, 0.f, 0.f};

  for (int ks = 0; ks < K; ks += 32) {
    const int kb = ks + kq * 8;
    short8v aHi[2], aLo[2];
#pragma unroll
    for (int rt = 0; rt < 2; ++rt) {
      int bo = ((rt * 16 + r16) * K + kb) * 2;
      int swz = bo ^ ((r16 & 7) << 4);
      aHi[rt] = *(const short8v*)((const char*)xsh + swz);
      aLo[rt] = *(const short8v*)((const char*)xsl + swz);
    }
#pragma unroll
    for (int ct = 0; ct < 4; ++ct) {
      const long wrow = (long)(col0 + ct * 16 + r16) * K + kb;
      short8v wHi = *(const short8v*)(WhiT + wrow);
      short8v wLo = *(const short8v*)(WloT + wrow);
#pragma unroll
      for (int rt = 0; rt < 2; ++rt) {
        acc[rt][ct] = __builtin_amdgcn_mfma_f32_16x16x32_bf16(aHi[rt], wHi, acc[rt][ct], 0, 0, 0);
        acc[rt][ct] = __builtin_amdgcn_mfma_f32_16x16x32_bf16(aHi[rt], wLo, acc[rt][ct], 0, 0, 0);
        acc[rt][ct] = __builtin_amdgcn_mfma_f32_16x16x32_bf16(aLo[rt], wHi, acc[rt][ct], 0, 0, 0);
      }
    }
  }

  float asv[4], adv[4];
#pragma unroll
  for (int ct = 0; ct < 4; ++ct) {
    int c = col0 + ct * 16 + r16;
    asv[ct] = a_src[c];
    adv[ct] = a_dst[c];
  }
#pragma unroll
  for (int rt = 0; rt < 2; ++rt) {
#pragma unroll
    for (int j = 0; j < 4; ++j) {
      const int r = rt * 16 + kq * 4 + j;           // row within block (0..31)
      const int g = n0 + r;                         // always < 20000
#pragma unroll
      for (int ct = 0; ct < 4; ++ct)
        hb[(long)g * FC + col0 + ct * 16 + r16] = f2bf(acc[rt][ct][j]);
      float ps = acc[rt][0][j] * asv[0] + acc[rt][1][j] * asv[1]
               + acc[rt][2][j] * asv[2] + acc[rt][3][j] * asv[3];
      float pd = acc[rt][0][j] * adv[0] + acc[rt][1][j] * adv[1]
               + acc[rt][2][j] * adv[2] + acc[rt][3][j] * adv[3];
      for (int off = 8; off; off >>= 1) {
        ps += __shfl_down(ps, off, 16);
        pd += __shfl_down(pd, off, 16);
      }
      if (r16 == 0) {
        asred[r][w] = ps;
        adred[r][w] = pd;
      }
    }
  }
  __syncthreads();
  if (t < 128) {                                    // 2 waves cover 32 rows
    const int rr = t >> 2, hh = t & 3;
    const int g = n0 + rr;
    float va = asred[rr][hh];
    as[(long)g * HEADSC + hh] = va;
    ad[(long)g * HEADSC + hh] = adred[rr][hh];
    float mv = va;
    for (int off = 32; off >= 4; off >>= 1) mv = fmaxf(mv, __shfl_down(mv, off, 64));
    if (l < 4) wmax[t >> 6][l] = mv;
  }
  __syncthreads();
  if (t < 4) atomicMaxF(&asmax[t], fmaxf(wmax[0][t], wmax[1][t]));
}

// ----------------------------- CSR build -----------------------------------
__global__ void deg_count(const int* __restrict__ ei, int* __restrict__ deg) {
  int e = blockIdx.x * 256 + threadIdx.x;
  if (e >= E_TOTC) return;
  atomicAdd(&deg[dstOf(ei, e)], 1);
}

// 1024-thread single-block scan, 2 barriers
__global__ void scan_kernel(const int* __restrict__ deg, int* __restrict__ row_ptr,
                            int* __restrict__ cursor) {
  const int t = threadIdx.x;
  const int lane = t & 63, wid = t >> 6;           // 16 waves
  const int PER = (N_NODESC + 1023) / 1024;        // 20
  const int base = t * PER;
  int own = 0;
  for (int i = 0; i < PER; ++i) {
    int idx = base + i;
    if (idx < N_NODESC) own += deg[idx];
  }
  int inc = own;
  for (int off = 1; off < 64; off <<= 1) {
    int v = __shfl_up(inc, off, 64);
    if (lane >= off) inc += v;
  }
  __shared__ int wtot[16], woff[16];
  if (lane == 63) wtot[wid] = inc;
  __syncthreads();
  if (t == 0) {
    int r = 0;
    for (int i = 0; i < 16; ++i) { woff[i] = r; r += wtot[i]; }
  }
  __syncthreads();
  int run = woff[wid] + inc - own;
  for (int i = 0; i < PER; ++i) {
    int idx = base + i;
    if (idx < N_NODESC) {
      row_ptr[idx] = run;
      cursor[idx]  = run;
      run += deg[idx];
    }
  }
  if (t == 1023) row_ptr[N_NODESC] = run;          // = E_TOTC
}

__global__ void fill_kernel(const int* __restrict__ ei, int* __restrict__ cursor,
                            int* __restrict__ col_src) {
  int e = blockIdx.x * 256 + threadIdx.x;
  if (e >= E_TOTC) return;
  int d = dstOf(ei, e);
  int pos = atomicAdd(&cursor[d], 1);
  col_src[pos] = srcOf(ei, e);
}

// --- FUSED softmax+agg, WAVE PER NODE (bound-stabilized, single pass) -------
// 256 threads = 4 waves = 4 nodes/block. Lane owns 4 channels (ushort4 = 8B).
// head h = lane>>4. Unroll-16 MLP batch (mean degree ~17). No barriers/LDS.
template<int MODE>
__global__ void __launch_bounds__(256) fused_sa(
    const int* __restrict__ row_ptr, const int* __restrict__ col_src,
    const float* __restrict__ asf, const float4* __restrict__ ad4,
    const float* __restrict__ asmax,
    const unsigned short* __restrict__ hb, const float* __restrict__ b,
    unsigned short* __restrict__ out_hi, unsigned short* __restrict__ out_lo,
    const float* __restrict__ W3, const float* __restrict__ asc3,
    const float* __restrict__ adc3, float* __restrict__ h3,
    float* __restrict__ a3s, float* __restrict__ a3d) {
  const int l = threadIdx.x & 63, wv = threadIdx.x >> 6;
  const int d = blockIdx.x * 4 + wv;                // 5000*4 = 20000 exact
  const int h = l >> 4;                             // head of 4-channel group
  const int j0 = row_ptr[d], j1 = row_ptr[d + 1];
  const float4 adv = ad4[d];
  const float advh = (h == 0) ? adv.x : (h == 1) ? adv.y : (h == 2) ? adv.z : adv.w;
  const float mh = lrelu(asmax[h] + advh);

  const ushort4* hb4 = (const ushort4*)hb;          // 64 quads per row
  float a0 = 0.f, a1 = 0.f, a2 = 0.f, a3 = 0.f, sm = 0.f;
  int j = j0;
  for (; j + 16 <= j1; j += 16) {
    int     s[16];
    float   av[16];
    ushort4 v[16];
#pragma unroll
    for (int u = 0; u < 16; ++u) s[u] = col_src[j + u];
#pragma unroll
    for (int u = 0; u < 16; ++u) av[u] = asf[s[u] * 4 + h];
#pragma unroll
    for (int u = 0; u < 16; ++u) v[u] = hb4[(long)s[u] * 64 + l];
#pragma unroll
    for (int u = 0; u < 16; ++u) {
      float e = expf(lrelu(av[u] + advh) - mh);
      sm += e;
      a0 = fmaf(e, bf2f(v[u].x), a0);
      a1 = fmaf(e, bf2f(v[u].y), a1);
      a2 = fmaf(e, bf2f(v[u].z), a2);
      a3 = fmaf(e, bf2f(v[u].w), a3);
    }
  }
  for (; j + 4 <= j1; j += 4) {
    int     s[4];
    float   av[4];
    ushort4 v[4];
#pragma unroll
    for (int u = 0; u < 4; ++u) s[u] = col_src[j + u];
#pragma unroll
    for (int u = 0; u < 4; ++u) av[u] = asf[s[u] * 4 + h];
#pragma unroll
    for (int u = 0; u < 4; ++u) v[u] = hb4[(long)s[u] * 64 + l];
#pragma unroll
    for (int u = 0; u < 4; ++u) {
      float e = expf(lrelu(av[u] + advh) - mh);
      sm += e;
      a0 = fmaf(e, bf2f(v[u].x), a0);
      a1 = fmaf(e, bf2f(v[u].y), a1);
      a2 = fmaf(e, bf2f(v[u].z), a2);
      a3 = fmaf(e, bf2f(v[u].w), a3);
    }
  }
  for (; j < j1; ++j) {
    int s = col_src[j];
    float e = expf(lrelu(asf[s * 4 + h] + advh) - mh);
    ushort4 v = hb4[(long)s * 64 + l];
    sm += e;
    a0 = fmaf(e, bf2f(v.x), a0);
    a1 = fmaf(e, bf2f(v.y), a1);
    a2 = fmaf(e, bf2f(v.z), a2);
    a3 = fmaf(e, bf2f(v.w), a3);
  }
  const float dn = 1.f / sm;
  float4 bb = *(const float4*)(b + 4 * l);
  float o0 = a0 * dn + bb.x;
  float o1 = a1 * dn + bb.y;
  float o2 = a2 * dn + bb.z;
  float o3 = a3 * dn + bb.w;
  o0 = o0 > 0.f ? o0 : expm1f(o0);                  // ELU
  o1 = o1 > 0.f ? o1 : expm1f(o1);
  o2 = o2 > 0.f ? o2 : expm1f(o2);
  o3 = o3 > 0.f ? o3 : expm1f(o3);

  if (MODE == 0) {
    ushort4 hi, lo;
    hi.x = f2bf(o0); lo.x = f2bf(o0 - bf2f(hi.x));
    hi.y = f2bf(o1); lo.y = f2bf(o1 - bf2f(hi.y));
    hi.z = f2bf(o2); lo.z = f2bf(o2 - bf2f(hi.z));
    hi.w = f2bf(o3); lo.w = f2bf(o3 - bf2f(hi.w));
    ((ushort4*)out_hi)[(long)d * 64 + l] = hi;
    ((ushort4*)out_lo)[(long)d * 64 + l] = lo;
  } else {
    // fused gemm3: p = o . W3 chunk; wave-reduce -> h3, alphas
    float4 w3 = *(const float4*)(W3 + 4 * l);
    float p = o0 * w3.x + o1 * w3.y + o2 * w3.z + o3 * w3.w;
    for (int off = 32; off; off >>= 1) p += __shfl_down(p, off, 64);
    if (l == 0) {
      h3[d]  = p;
      a3s[d] = p * asc3[0];
      a3d[d] = p * adc3[0];
    }
  }
}

// --- FUSED layer3 softmax+agg: out = sum(e*h3)/sum(e), wave per node -------
__global__ void __launch_bounds__(256) fused_sa3(
    const int* __restrict__ row_ptr, const int* __restrict__ col_src,
    const float* __restrict__ as, const float* __restrict__ ad,
    const float* __restrict__ h3, const float* __restrict__ b3,
    float* __restrict__ out) {
  const int wv = threadIdx.x >> 6, l = threadIdx.x & 63;
  const int d = blockIdx.x * 4 + wv;
  if (d >= N_NODESC) return;
  const int j0 = row_ptr[d], j1 = row_ptr[d + 1];
  const float adv = ad[d];
  float mx = -INFINITY;
  for (int j = j0 + l; j < j1; j += 64)
    mx = fmaxf(mx, lrelu(as[col_src[j]] + adv));
  for (int off = 32; off; off >>= 1) mx = fmaxf(mx, __shfl_xor(mx, off, 64));
  float sm = 0.f, acc = 0.f;
  for (int j = j0 + l; j < j1; j += 64) {
    int s = col_src[j];
    float e = expf(lrelu(as[s] + adv) - mx);
    sm += e;
    acc = fmaf(e, h3[s], acc);
  }
  for (int off = 32; off; off >>= 1) {
    sm  += __shfl_xor(sm, off, 64);
    acc += __shfl_xor(acc, off, 64);
  }
  if (l == 0) out[d] = acc / sm + b3[0];
}

extern "C" void kernel_launch(void* const* d_in, const int* in_sizes, int n_in,
                              void* d_out, int out_size, void* d_ws, size_t ws_size,
                              hipStream_t stream) {
  const float* x    = (const float*)d_in[0];
  const int*   ei   = (const int*)d_in[1];
  const float* W1   = (const float*)d_in[2];
  const float* as1  = (const float*)d_in[3];
  const float* ad1  = (const float*)d_in[4];
  const float* b1   = (const float*)d_in[5];
  const float* W2   = (const float*)d_in[6];
  const float* as2  = (const float*)d_in[7];
  const float* ad2  = (const float*)d_in[8];
  const float* b2   = (const float*)d_in[9];
  const float* W3   = (const float*)d_in[10];
  const float* as3  = (const float*)d_in[11];
  const float* ad3  = (const float*)d_in[12];
  const float* b3   = (const float*)d_in[13];
  float* out = (float*)d_out;

  float* ws = (float*)d_ws;
  size_t off = 0;
  float* wAs   = ws + off; off += (size_t)N_NODESC * HEADSC;
  float* wAd   = ws + off; off += (size_t)N_NODESC * HEADSC;
  float* h3    = ws + off; off += N_NODESC;
  float* a3s   = ws + off; off += N_NODESC;
  float* a3d   = ws + off; off += N_NODESC;
  float* amax  = ws + off; off += 8;                // [0..3]=layer1, [4..7]=layer2
  int* deg     = (int*)(ws + off); off += N_NODESC;
  int* row_ptr = (int*)(ws + off); off += N_NODESC + 1;
  int* cursor  = (int*)(ws + off); off += N_NODESC;
  int* col_src = (int*)(ws + off); off += E_TOTC;
  off = (off + 3) & ~(size_t)3;                     // 16B align for bf16 vectors
  unsigned short* hb     = (unsigned short*)(ws + off); off += (size_t)N_NODESC * 128;
  unsigned short* act_hi = (unsigned short*)(ws + off); off += (size_t)N_NODESC * 128;
  unsigned short* act_lo = (unsigned short*)(ws + off); off += (size_t)N_NODESC * 128;
  unsigned short* xhi    = (unsigned short*)(ws + off); off += (size_t)N_NODESC * 64;
  unsigned short* xlo    = (unsigned short*)(ws + off); off += (size_t)N_NODESC * 64;
  unsigned short* W1hiT  = (unsigned short*)(ws + off); off += 16384;   // 32768 ush
  unsigned short* W1loT  = (unsigned short*)(ws + off); off += 16384;
  unsigned short* W2hiT  = (unsigned short*)(ws + off); off += 32768;   // 65536 ush
  unsigned short* W2loT  = (unsigned short*)(ws + off); off += 32768;

  const int gridE  = (E_TOTC + 255) / 256;
  const int gridN4 = (N_NODESC + 3) / 4;
  const int gemmG  = N_NODESC / 32;                 // 625, exact

  // ---------------- prep (1 dispatch) + CSR build --------------------------
  mega_prep<<<10463, 256, 0, stream>>>(x, xhi, xlo, W1, W1hiT, W1loT,
                                       W2, W2hiT, W2loT, deg, amax);
  deg_count<<<gridE, 256, 0, stream>>>(ei, deg);
  scan_kernel<<<1, 1024, 0, stream>>>(deg, row_ptr, cursor);
  fill_kernel<<<gridE, 256, 0, stream>>>(ei, cursor, col_src);

  // ---------------- layer 1 (K=128) ----------------
  mfma_gemm<128><<<gemmG, 256, 0, stream>>>(xhi, xlo, W1hiT, W1loT, as1, ad1,
                                            hb, wAs, wAd, amax);
  fused_sa<0><<<N_NODESC / 4, 256, 0, stream>>>(row_ptr, col_src, wAs, (const float4*)wAd,
                                                amax, hb, b1, act_hi, act_lo,
                                                nullptr, nullptr, nullptr, nullptr, nullptr, nullptr);

  // ---------------- layer 2 (K=256), gemm3 fused into epilogue -------------
  mfma_gemm<256><<<gemmG, 256, 0, stream>>>(act_hi, act_lo, W2hiT, W2loT, as2, ad2,
                                            hb, wAs, wAd, amax + 4);
  fused_sa<1><<<N_NODESC / 4, 256, 0, stream>>>(row_ptr, col_src, wAs, (const float4*)wAd,
                                                amax + 4, hb, b2, nullptr, nullptr,
                                                W3, as3, ad3, h3, a3s, a3d);

  // ---------------- layer 3 (heads=1, out=1) ----------------
  fused_sa3<<<gridN4, 256, 0, stream>>>(row_ptr, col_src, a3s, a3d, h3, b3, out);
}